// Round 3
// baseline (680.119 us; speedup 1.0000x reference)
//
#include <hip/hip_runtime.h>

#define NPTS 1048576

#define DHW0 (32 * 32 * 32)
#define DHW1 (64 * 64 * 64)
#define DHW2 (128 * 128 * 128)
#define DHW3 (256 * 256 * 256)

typedef float v4f __attribute__((ext_vector_type(4)));

__device__ __forceinline__ void nt_store4(const float4 f, float4* p) {
    __builtin_nontemporal_store(*(const v4f*)&f, (v4f*)p);
}

// ---------------- math helpers ----------------

__device__ __forceinline__ float4 lerp4(const float4 a, const float4 b, const float t) {
    return make_float4(a.x + (b.x - a.x) * t,
                       a.y + (b.y - a.y) * t,
                       a.z + (b.z - a.z) * t,
                       a.w + (b.w - a.w) * t);
}

struct CoordW { float tx, ty, tz; int b00, b01, b10, b11, x0, x1; };

template<int D>
__device__ __forceinline__ CoordW mkcoord(float gx, float gy, float gz) {
    CoordW c;
    float x = fminf(fmaxf((gx + 1.0f) * (0.5f * (float)(D - 1)), 0.0f), (float)(D - 1));
    float y = fminf(fmaxf((gy + 1.0f) * (0.5f * (float)(D - 1)), 0.0f), (float)(D - 1));
    float z = fminf(fmaxf((gz + 1.0f) * (0.5f * (float)(D - 1)), 0.0f), (float)(D - 1));
    float xf = floorf(x), yf = floorf(y), zf = floorf(z);
    float tx = x - xf, ty = y - yf, tz = z - zf;
    c.tx = tx * tx * (3.0f - 2.0f * tx);
    c.ty = ty * ty * (3.0f - 2.0f * ty);
    c.tz = tz * tz * (3.0f - 2.0f * tz);
    int x0 = (int)xf, y0 = (int)yf, z0 = (int)zf;
    int y1 = min(y0 + 1, D - 1), z1 = min(z0 + 1, D - 1);
    c.x0 = x0;
    c.x1 = min(x0 + 1, D - 1);
    c.b00 = (z0 * D + y0) * D;
    c.b01 = (z0 * D + y1) * D;
    c.b10 = (z1 * D + y0) * D;
    c.b11 = (z1 * D + y1) * D;
    return c;
}

__device__ __forceinline__ float4 reduce8(const float4* q, const CoordW& c) {
    float4 c00 = lerp4(q[0], q[1], c.tx);
    float4 c01 = lerp4(q[2], q[3], c.tx);
    float4 c10 = lerp4(q[4], q[5], c.tx);
    float4 c11 = lerp4(q[6], q[7], c.tx);
    float4 c0 = lerp4(c00, c01, c.ty);
    float4 c1 = lerp4(c10, c11, c.ty);
    return lerp4(c0, c1, c.tz);
}

// trilinear for the native-layout 256^3 volume from 16 float2 row-pairs
__device__ __forceinline__ float4 reduce_v3(const float2* qd, const CoordW& c, bool edge) {
    float r[4];
#pragma unroll
    for (int ch = 0; ch < 4; ++ch) {
        float v00a = edge ? qd[ch * 4 + 0].y : qd[ch * 4 + 0].x, v00b = qd[ch * 4 + 0].y;
        float v01a = edge ? qd[ch * 4 + 1].y : qd[ch * 4 + 1].x, v01b = qd[ch * 4 + 1].y;
        float v10a = edge ? qd[ch * 4 + 2].y : qd[ch * 4 + 2].x, v10b = qd[ch * 4 + 2].y;
        float v11a = edge ? qd[ch * 4 + 3].y : qd[ch * 4 + 3].x, v11b = qd[ch * 4 + 3].y;
        float c00 = v00a + (v00b - v00a) * c.tx;
        float c01 = v01a + (v01b - v01a) * c.tx;
        float c10 = v10a + (v10b - v10a) * c.tx;
        float c11 = v11a + (v11b - v11a) * c.tx;
        float e0 = c00 + (c01 - c00) * c.ty;
        float e1 = c10 + (c11 - c10) * c.ty;
        r[ch] = e0 + (e1 - e0) * c.tz;
    }
    return make_float4(r[0], r[1], r[2], r[3]);
}

// coalesced 16-stream output store (consecutive p across lanes -> full lines)
__device__ __forceinline__ void store16(const float4 f0, const float4 f1,
                                        const float4 f2, const float4 f3,
                                        float* __restrict__ out, int p) {
    __builtin_nontemporal_store(f0.x, &out[ 0 * NPTS + p]);
    __builtin_nontemporal_store(f0.y, &out[ 1 * NPTS + p]);
    __builtin_nontemporal_store(f0.z, &out[ 2 * NPTS + p]);
    __builtin_nontemporal_store(f0.w, &out[ 3 * NPTS + p]);
    __builtin_nontemporal_store(f1.x, &out[ 4 * NPTS + p]);
    __builtin_nontemporal_store(f1.y, &out[ 5 * NPTS + p]);
    __builtin_nontemporal_store(f1.z, &out[ 6 * NPTS + p]);
    __builtin_nontemporal_store(f1.w, &out[ 7 * NPTS + p]);
    __builtin_nontemporal_store(f2.x, &out[ 8 * NPTS + p]);
    __builtin_nontemporal_store(f2.y, &out[ 9 * NPTS + p]);
    __builtin_nontemporal_store(f2.z, &out[10 * NPTS + p]);
    __builtin_nontemporal_store(f2.w, &out[11 * NPTS + p]);
    __builtin_nontemporal_store(f3.x, &out[12 * NPTS + p]);
    __builtin_nontemporal_store(f3.y, &out[13 * NPTS + p]);
    __builtin_nontemporal_store(f3.z, &out[14 * NPTS + p]);
    __builtin_nontemporal_store(f3.w, &out[15 * NPTS + p]);
}

// ---------------- transpose [C,DHW] -> [DHW,C] ----------------
// ranges: w2, w1, w0, then (optional, w3 != null) v3 -> w3.

__global__ __launch_bounds__(256) void xpose_kernel(
    const float* __restrict__ v0, const float* __restrict__ v1,
    const float* __restrict__ v2, const float* __restrict__ v3,
    float4* __restrict__ w0, float4* __restrict__ w1,
    float4* __restrict__ w2, float4* __restrict__ w3)
{
    constexpr int B2 = DHW2 / 256, B1 = DHW1 / 256, B0 = DHW0 / 256;
    int b = blockIdx.x;
    int t = threadIdx.x;
    if (b < B2) {
        int v = b * 256 + t;
        w2[v] = make_float4(v2[v], v2[v + DHW2], v2[v + 2 * DHW2], v2[v + 3 * DHW2]);
    } else if (b < B2 + B1) {
        int v = (b - B2) * 256 + t;
        w1[v] = make_float4(v1[v], v1[v + DHW1], v1[v + 2 * DHW1], v1[v + 3 * DHW1]);
    } else if (b < B2 + B1 + B0) {
        int v = (b - B2 - B1) * 256 + t;
        w0[v] = make_float4(v0[v], v0[v + DHW0], v0[v + 2 * DHW0], v0[v + 3 * DHW0]);
    } else {
        int v = (b - B2 - B1 - B0) * 256 + t;
        // NT store: don't let 256MB of w3 writes evict w0..w2 from L2/L3
        nt_store4(make_float4(v3[v], v3[v + DHW3], v3[v + 2 * DHW3], v3[v + 3 * DHW3]),
                  w3 + v);
    }
}

// ---------------- fused main kernel, ORIGINAL point order (no sort) ----------------
// 40 loads issued before any arithmetic (issue order == consume order, v3 last
// so FIFO vmcnt lets f0..f2 math run while v3/HBM loads are in flight), pinned
// by sched_barrier(0). NT stores straight to out: coalesced 16 streams, and no
// L2/L3 pollution (L3 is reserved for v3, which is exactly LLC-sized).

__global__ __launch_bounds__(256, 3) void mg_fused_kernel(
    const float* __restrict__ grid,
    const float4* __restrict__ w0, const float4* __restrict__ w1,
    const float4* __restrict__ w2, const float* __restrict__ v3,
    float* __restrict__ out)
{
    int p = blockIdx.x * 256 + (int)threadIdx.x;
    float gx = grid[3 * p + 0];
    float gy = grid[3 * p + 1];
    float gz = grid[3 * p + 2];

    CoordW c0 = mkcoord<32>(gx, gy, gz);
    CoordW c1 = mkcoord<64>(gx, gy, gz);
    CoordW c2 = mkcoord<128>(gx, gy, gz);
    CoordW c3 = mkcoord<256>(gx, gy, gz);
    const int  xm = min(c3.x0, 254);
    const bool edge = (c3.x0 == 255);

    float4 qa[8], qb[8], qc[8];
    float2 qd[16];

    qa[0] = w0[c0.b00 + c0.x0]; qa[1] = w0[c0.b00 + c0.x1];
    qa[2] = w0[c0.b01 + c0.x0]; qa[3] = w0[c0.b01 + c0.x1];
    qa[4] = w0[c0.b10 + c0.x0]; qa[5] = w0[c0.b10 + c0.x1];
    qa[6] = w0[c0.b11 + c0.x0]; qa[7] = w0[c0.b11 + c0.x1];

    qb[0] = w1[c1.b00 + c1.x0]; qb[1] = w1[c1.b00 + c1.x1];
    qb[2] = w1[c1.b01 + c1.x0]; qb[3] = w1[c1.b01 + c1.x1];
    qb[4] = w1[c1.b10 + c1.x0]; qb[5] = w1[c1.b10 + c1.x1];
    qb[6] = w1[c1.b11 + c1.x0]; qb[7] = w1[c1.b11 + c1.x1];

    qc[0] = w2[c2.b00 + c2.x0]; qc[1] = w2[c2.b00 + c2.x1];
    qc[2] = w2[c2.b01 + c2.x0]; qc[3] = w2[c2.b01 + c2.x1];
    qc[4] = w2[c2.b10 + c2.x0]; qc[5] = w2[c2.b10 + c2.x1];
    qc[6] = w2[c2.b11 + c2.x0]; qc[7] = w2[c2.b11 + c2.x1];

#pragma unroll
    for (int ch = 0; ch < 4; ++ch) {
        const float* __restrict__ vc = v3 + (size_t)ch * DHW3;
        qd[ch * 4 + 0] = *(const float2*)(vc + c3.b00 + xm);
        qd[ch * 4 + 1] = *(const float2*)(vc + c3.b01 + xm);
        qd[ch * 4 + 2] = *(const float2*)(vc + c3.b10 + xm);
        qd[ch * 4 + 3] = *(const float2*)(vc + c3.b11 + xm);
    }

    __builtin_amdgcn_sched_barrier(0);

    float4 f0 = reduce8(qa, c0);
    float4 f1 = reduce8(qb, c1);
    float4 f2 = reduce8(qc, c2);
    float4 f3 = reduce_v3(qd, c3, edge);

    store16(f0, f1, f2, f3, out, p);
}

// variant with v3 also transposed ([DHW][4]): per row one 32B pair of float4s
// -> v3 line-touches drop ~4x (16 -> ~4-6 per point).

__global__ __launch_bounds__(256, 3) void mg_fused_w3_kernel(
    const float* __restrict__ grid,
    const float4* __restrict__ w0, const float4* __restrict__ w1,
    const float4* __restrict__ w2, const float4* __restrict__ w3,
    float* __restrict__ out)
{
    int p = blockIdx.x * 256 + (int)threadIdx.x;
    float gx = grid[3 * p + 0];
    float gy = grid[3 * p + 1];
    float gz = grid[3 * p + 2];

    CoordW c0 = mkcoord<32>(gx, gy, gz);
    CoordW c1 = mkcoord<64>(gx, gy, gz);
    CoordW c2 = mkcoord<128>(gx, gy, gz);
    CoordW c3 = mkcoord<256>(gx, gy, gz);
    const int  xm = min(c3.x0, 254);
    const bool edge = (c3.x0 == 255);

    float4 qa[8], qb[8], qc[8], qlo[4], qhi[4];

    qa[0] = w0[c0.b00 + c0.x0]; qa[1] = w0[c0.b00 + c0.x1];
    qa[2] = w0[c0.b01 + c0.x0]; qa[3] = w0[c0.b01 + c0.x1];
    qa[4] = w0[c0.b10 + c0.x0]; qa[5] = w0[c0.b10 + c0.x1];
    qa[6] = w0[c0.b11 + c0.x0]; qa[7] = w0[c0.b11 + c0.x1];

    qb[0] = w1[c1.b00 + c1.x0]; qb[1] = w1[c1.b00 + c1.x1];
    qb[2] = w1[c1.b01 + c1.x0]; qb[3] = w1[c1.b01 + c1.x1];
    qb[4] = w1[c1.b10 + c1.x0]; qb[5] = w1[c1.b10 + c1.x1];
    qb[6] = w1[c1.b11 + c1.x0]; qb[7] = w1[c1.b11 + c1.x1];

    qc[0] = w2[c2.b00 + c2.x0]; qc[1] = w2[c2.b00 + c2.x1];
    qc[2] = w2[c2.b01 + c2.x0]; qc[3] = w2[c2.b01 + c2.x1];
    qc[4] = w2[c2.b10 + c2.x0]; qc[5] = w2[c2.b10 + c2.x1];
    qc[6] = w2[c2.b11 + c2.x0]; qc[7] = w2[c2.b11 + c2.x1];

    qlo[0] = w3[c3.b00 + xm]; qhi[0] = w3[c3.b00 + xm + 1];
    qlo[1] = w3[c3.b01 + xm]; qhi[1] = w3[c3.b01 + xm + 1];
    qlo[2] = w3[c3.b10 + xm]; qhi[2] = w3[c3.b10 + xm + 1];
    qlo[3] = w3[c3.b11 + xm]; qhi[3] = w3[c3.b11 + xm + 1];

    __builtin_amdgcn_sched_barrier(0);

    float4 f0 = reduce8(qa, c0);
    float4 f1 = reduce8(qb, c1);
    float4 f2 = reduce8(qc, c2);

    float4 a00 = edge ? qhi[0] : qlo[0];
    float4 a01 = edge ? qhi[1] : qlo[1];
    float4 a10 = edge ? qhi[2] : qlo[2];
    float4 a11 = edge ? qhi[3] : qlo[3];
    float4 r00 = lerp4(a00, qhi[0], c3.tx);
    float4 r01 = lerp4(a01, qhi[1], c3.tx);
    float4 r10 = lerp4(a10, qhi[2], c3.tx);
    float4 r11 = lerp4(a11, qhi[3], c3.tx);
    float4 e0 = lerp4(r00, r01, c3.ty);
    float4 e1 = lerp4(r10, r11, c3.ty);
    float4 f3 = lerp4(e0, e1, c3.tz);

    store16(f0, f1, f2, f3, out, p);
}

// ---------------- no-workspace fallback ----------------

template<int D>
__device__ __forceinline__ float4 sample_direct(const float* __restrict__ v,
                                                float gx, float gy, float gz) {
    CoordW c = mkcoord<D>(gx, gy, gz);
    float r[4];
#pragma unroll
    for (int ch = 0; ch < 4; ++ch) {
        const float* __restrict__ vc = v + (size_t)ch * (D * D * D);
        float c000 = vc[c.b00 + c.x0], c001 = vc[c.b00 + c.x1];
        float c010 = vc[c.b01 + c.x0], c011 = vc[c.b01 + c.x1];
        float c100 = vc[c.b10 + c.x0], c101 = vc[c.b10 + c.x1];
        float c110 = vc[c.b11 + c.x0], c111 = vc[c.b11 + c.x1];
        float c00 = c000 + (c001 - c000) * c.tx;
        float c01 = c010 + (c011 - c010) * c.tx;
        float c10 = c100 + (c101 - c100) * c.tx;
        float c11 = c110 + (c111 - c110) * c.tx;
        float e0 = c00 + (c01 - c00) * c.ty;
        float e1 = c10 + (c11 - c10) * c.ty;
        r[ch] = e0 + (e1 - e0) * c.tz;
    }
    return make_float4(r[0], r[1], r[2], r[3]);
}

__global__ __launch_bounds__(256) void mg_direct_kernel(
    const float* __restrict__ grid,
    const float* __restrict__ v0, const float* __restrict__ v1,
    const float* __restrict__ v2, const float* __restrict__ v3,
    float* __restrict__ out)
{
    int p = blockIdx.x * blockDim.x + threadIdx.x;
    float gx = grid[3 * p + 0];
    float gy = grid[3 * p + 1];
    float gz = grid[3 * p + 2];
    float4 f0 = sample_direct<32>(v0, gx, gy, gz);
    float4 f1 = sample_direct<64>(v1, gx, gy, gz);
    float4 f2 = sample_direct<128>(v2, gx, gy, gz);
    float4 f3 = sample_direct<256>(v3, gx, gy, gz);
    store16(f0, f1, f2, f3, out, p);
}

// ---------------- launch ----------------

extern "C" void kernel_launch(void* const* d_in, const int* in_sizes, int n_in,
                              void* d_out, int out_size, void* d_ws, size_t ws_size,
                              hipStream_t stream) {
    const float* grid = (const float*)d_in[0];
    const float* v0   = (const float*)d_in[1];   // [4,32,32,32]
    const float* v1   = (const float*)d_in[2];   // [4,64,64,64]
    const float* v2   = (const float*)d_in[3];   // [4,128,128,128]
    const float* v3   = (const float*)d_in[4];   // [4,256,256,256]
    float* out = (float*)d_out;

    constexpr size_t WS_INTER = (size_t)(DHW0 + DHW1 + DHW2) * 16;        // 36.5 MB
    constexpr size_t WS_W3    = WS_INTER + (size_t)DHW3 * 16;             // 292.5 MB

    const int threads = 256;
    const int pt_blocks = NPTS / threads;   // 4096
    constexpr int xb_small = (DHW0 + DHW1 + DHW2) / 256;   // 9344
    constexpr int xb_v3    = DHW3 / 256;                   // 65536

    if (ws_size >= WS_W3) {
        float4* w0 = (float4*)d_ws;
        float4* w1 = w0 + DHW0;
        float4* w2 = w1 + DHW1;
        float4* w3 = w2 + DHW2;
        xpose_kernel<<<xb_small + xb_v3, threads, 0, stream>>>(
            v0, v1, v2, v3, w0, w1, w2, w3);
        mg_fused_w3_kernel<<<pt_blocks, threads, 0, stream>>>(
            grid, w0, w1, w2, w3, out);
    } else if (ws_size >= WS_INTER) {
        float4* w0 = (float4*)d_ws;
        float4* w1 = w0 + DHW0;
        float4* w2 = w1 + DHW1;
        xpose_kernel<<<xb_small, threads, 0, stream>>>(
            v0, v1, v2, v3, w0, w1, w2, (float4*)nullptr);
        mg_fused_kernel<<<pt_blocks, threads, 0, stream>>>(
            grid, w0, w1, w2, v3, out);
    } else {
        mg_direct_kernel<<<pt_blocks, threads, 0, stream>>>(grid, v0, v1, v2, v3, out);
    }
}